// Round 6
// baseline (224.677 us; speedup 1.0000x reference)
//
#include <hip/hip_runtime.h>
#include <hip/hip_bf16.h>

// Problem constants (from reference)
#define DFEAT   64
#define NREL    8
#define KDIM    512     // DFEAT * NREL
#define DOUT    64
#define NBASES  4

#define CHSZ    128     // dst-chunk size (power of 2: bin index = d >> 7)
#define NCB_MAX 400     // max chunks with LDS bins / compile-time arrays
#define OVFC    400     // cursor slot index of the overflow counter
#define CSTR    32      // cursor stride in ints = 128 B (one cache line/counter)
#define EPB     2048    // edges per binning block (256 thr x 8)
#define CAPB    12      // LDS bin slots/chunk; lambda 5.24 -> P(>12) ~ 0.3%
#define SORTMX  2944    // max records sorted per chunk (= slab_cap cap)

typedef short short8 __attribute__((ext_vector_type(8)));    // 8 bf16 = 4 VGPRs
typedef float f32x4  __attribute__((ext_vector_type(4)));    // MFMA C/D frag
typedef unsigned short ushort8 __attribute__((ext_vector_type(8)));  // 16B

// fp32 -> bf16 round-to-nearest-even (bit pattern)
__device__ __forceinline__ unsigned short f2bf(float f) {
    unsigned u = __float_as_uint(f);
    u += 0x7fff + ((u >> 16) & 1);
    return (unsigned short)(u >> 16);
}
__device__ __forceinline__ float bf2f(unsigned short b) {
    return __uint_as_float(((unsigned)b) << 16);
}

// ---------------------------------------------------------------------------
// K1: wT[o][k] = bf16( sum_b w_rel[r,b] * w_bases[b,i,o] ),  k = i*8+r.
// Also zeros the (line-padded) chunk cursors + overflow cursor.
// ---------------------------------------------------------------------------
__global__ __launch_bounds__(256) void weight_kernel(
    const float* __restrict__ w_rel,    // [NREL][NBASES]
    const float* __restrict__ w_bases,  // [NBASES][DFEAT][DOUT]
    unsigned short* __restrict__ wT,    // [DOUT][KDIM] bf16 bits
    int* __restrict__ cursor)
{
    int idx = blockIdx.x * 256 + threadIdx.x;   // 0..32767
    int k = idx & 511;     // i*8 + r
    int o = idx >> 9;      // 0..63
    int i = k >> 3;
    int r = k & 7;
    float s = 0.f;
#pragma unroll
    for (int b = 0; b < NBASES; ++b)
        s += w_rel[r * NBASES + b] * w_bases[(b * DFEAT + i) * DOUT + o];
    wT[o * KDIM + k] = f2bf(s);

    if (idx < (OVFC + 8) * CSTR) cursor[idx] = 0;
}

// LDS overlay: transform blocks use ylds, binning blocks use b. (~40 KB)
union SharedK2 {
    unsigned short ylds[4][16][64];            // 8 KB
    struct {
        uint2 bin[NCB_MAX][CAPB];              // 38.4 KB
        int bcnt[NCB_MAX];                     // 1.6 KB
    } b;
};

// ---------------------------------------------------------------------------
// Fused K2: grid-partitioned. BIN blocks dispatched FIRST so the kernel's
// tail is the well-pipelined transform stream.
//   blocks [0, p_blocks):  BIN — LDS bins by dst-chunk (c = d>>7), flushed
//     one-thread-per-bin into per-chunk slabs; cursor counters are padded
//     one-per-cache-line so flush/fallback atomics pipeline in L2 instead
//     of ping-ponging shared lines across XCDs.
//   blocks [p_blocks, ..): transform  Y = Xflat @ Wflat via bf16 MFMA.
//     Explicit register double-buffer: prefetch next 128-K group (8 x
//     float4, static indices) while MFMAing current -> 8 HBM loads always
//     in flight (r5's VGPR=56 showed the scheduler alone kept only ~2).
// ---------------------------------------------------------------------------
__global__ __launch_bounds__(256) void fused_kernel(
    const float* __restrict__ x,    // [n_nodes][KDIM] fp32
    const unsigned short* __restrict__ wT,   // [DOUT][KDIM] bf16
    unsigned short* __restrict__ y, // [n_nodes][DOUT] bf16
    int n_nodes,
    const int* __restrict__ esrc, const int* __restrict__ edst,
    const float* __restrict__ ew,
    int* __restrict__ cursor,
    uint2* __restrict__ slab, uint2* __restrict__ ovf,
    int n_edges, int nc, int slab_cap, int ovf_cap, int p_blocks)
{
    const int tid = threadIdx.x;
    __shared__ SharedK2 sh;

    if (blockIdx.x < p_blocks) {
        // ---- bin phase ----
        auto& B = sh.b;
        const int lim = nc < NCB_MAX ? nc : NCB_MAX;
        for (int i = tid; i < lim; i += 256) B.bcnt[i] = 0;
        __syncthreads();

        int e0 = blockIdx.x * EPB + tid;
#pragma unroll
        for (int j = 0; j < EPB / 256; ++j) {
            int e = e0 + j * 256;
            if (e < n_edges) {
                int d = edst[e];
                unsigned entry = (unsigned)(esrc[e] & 0xFFFF)
                               | ((unsigned)f2bf(ew[e]) << 16);
                int c = d >> 7;                        // d / CHSZ
                uint2 rec = make_uint2(entry, (unsigned)d);
                int pos = (c < NCB_MAX) ? atomicAdd(&B.bcnt[c], 1) : CAPB;
                if (pos < CAPB) {
                    B.bin[c][pos] = rec;
                } else {  // LDS bin overflow (~0.3%): direct append
                    int p = atomicAdd(&cursor[c * CSTR], 1);
                    if (p < slab_cap) slab[(size_t)c * slab_cap + p] = rec;
                    else { int q = atomicAdd(&cursor[OVFC * CSTR], 1);
                           if (q < ovf_cap) ovf[q] = rec; }
                }
            }
        }
        __syncthreads();

        // ---- flush: one thread per bin (atomics on distinct lines) ----
        for (int c = tid; c < lim; c += 256) {
            int n = B.bcnt[c]; if (n > CAPB) n = CAPB;
            int bb = atomicAdd(&cursor[c * CSTR], n);
            uint2* sc = slab + (size_t)c * slab_cap;
            for (int i = 0; i < n; ++i) {
                uint2 rec = B.bin[c][i];
                int p = bb + i;
                if (p < slab_cap) sc[p] = rec;
                else { int q = atomicAdd(&cursor[OVFC * CSTR], 1);
                       if (q < ovf_cap) ovf[q] = rec; }
            }
        }
        return;
    }

    // ---- transform phase ----
    const int bidx = blockIdx.x - p_blocks;
    const int wid  = tid >> 6;
    const int lane = tid & 63;
    const int quad = lane >> 4;    // 0..3
    const int fi   = lane & 15;    // 0..15

    const int node0 = (bidx * 4 + wid) * 16;
    int myrow = node0 + fi;
    if (myrow >= n_nodes) myrow = n_nodes - 1;
    const float* xg = x + (size_t)myrow * KDIM + quad * 8;
    const unsigned short* wg = wT + fi * KDIM + quad * 8;

    f32x4 acc0 = {0.f, 0.f, 0.f, 0.f};
    f32x4 acc1 = {0.f, 0.f, 0.f, 0.f};
    f32x4 acc2 = {0.f, 0.f, 0.f, 0.f};
    f32x4 acc3 = {0.f, 0.f, 0.f, 0.f};

    // register double-buffer: 8 float4 of the NEXT 128-K group in flight
    float4 xa0, xa1, xa2, xa3, xb0, xb1, xb2, xb3;
    xa0 = *(const float4*)(xg +   0); xb0 = *(const float4*)(xg +   4);
    xa1 = *(const float4*)(xg +  32); xb1 = *(const float4*)(xg +  36);
    xa2 = *(const float4*)(xg +  64); xb2 = *(const float4*)(xg +  68);
    xa3 = *(const float4*)(xg +  96); xb3 = *(const float4*)(xg + 100);

#pragma unroll 1
    for (int km = 0; km < KDIM; km += 128) {
        float4 na0, na1, na2, na3, nb0, nb1, nb2, nb3;
        if (km + 128 < KDIM) {
            const float* xn = xg + km + 128;
            na0 = *(const float4*)(xn +   0); nb0 = *(const float4*)(xn +   4);
            na1 = *(const float4*)(xn +  32); nb1 = *(const float4*)(xn +  36);
            na2 = *(const float4*)(xn +  64); nb2 = *(const float4*)(xn +  68);
            na3 = *(const float4*)(xn +  96); nb3 = *(const float4*)(xn + 100);
        }
#define XSTEP(XA, XB, U)                                                      \
        {                                                                     \
            short8 a;                                                         \
            a[0]=f2bf(XA.x); a[1]=f2bf(XA.y); a[2]=f2bf(XA.z); a[3]=f2bf(XA.w);\
            a[4]=f2bf(XB.x); a[5]=f2bf(XB.y); a[6]=f2bf(XB.z); a[7]=f2bf(XB.w);\
            int kb = km + (U) * 32;                                           \
            short8 b0 = *(const short8*)(wg + kb);                            \
            short8 b1 = *(const short8*)(wg + 16 * KDIM + kb);                \
            short8 b2 = *(const short8*)(wg + 32 * KDIM + kb);                \
            short8 b3 = *(const short8*)(wg + 48 * KDIM + kb);                \
            acc0 = __builtin_amdgcn_mfma_f32_16x16x32_bf16(a, b0, acc0, 0,0,0);\
            acc1 = __builtin_amdgcn_mfma_f32_16x16x32_bf16(a, b1, acc1, 0,0,0);\
            acc2 = __builtin_amdgcn_mfma_f32_16x16x32_bf16(a, b2, acc2, 0,0,0);\
            acc3 = __builtin_amdgcn_mfma_f32_16x16x32_bf16(a, b3, acc3, 0,0,0);\
        }
        XSTEP(xa0, xb0, 0)
        XSTEP(xa1, xb1, 1)
        XSTEP(xa2, xb2, 2)
        XSTEP(xa3, xb3, 3)
#undef XSTEP
        xa0 = na0; xb0 = nb0; xa1 = na1; xb1 = nb1;
        xa2 = na2; xb2 = nb2; xa3 = na3; xb3 = nb3;
    }

    // epilogue: C layout col=fi, row=quad*4+r -> stage to LDS, store b128
#pragma unroll
    for (int r = 0; r < 4; ++r) {
        int n = quad * 4 + r;
        sh.ylds[wid][n][fi]      = f2bf(acc0[r]);
        sh.ylds[wid][n][16 + fi] = f2bf(acc1[r]);
        sh.ylds[wid][n][32 + fi] = f2bf(acc2[r]);
        sh.ylds[wid][n][48 + fi] = f2bf(acc3[r]);
    }
    __syncthreads();   // uniform: no transform wave returned early

    int nl = lane >> 2;            // node_local 0..15
    int cg = (lane & 3) * 16;      // 16-short chunk within the 64-col row
    int node = node0 + nl;
    if (node < n_nodes) {
        ushort8 v0 = *(const ushort8*)&sh.ylds[wid][nl][cg];
        ushort8 v1 = *(const ushort8*)&sh.ylds[wid][nl][cg + 8];
        unsigned short* yr = y + (size_t)node * DOUT + cg;
        *(ushort8*)yr       = v0;
        *(ushort8*)(yr + 8) = v1;
    }
}

// ---------------------------------------------------------------------------
// K3: aggregate — counting-sort in LDS, then pure-register gather.
// (structure unchanged from r5 — it dropped out of the top-5; only the
// padded-cursor indexing changed)
// ---------------------------------------------------------------------------
__global__ __launch_bounds__(1024, 4) void aggregate_kernel(
    const uint2* __restrict__ slab, const uint2* __restrict__ ovf,
    const int* __restrict__ cursor,
    const unsigned short* __restrict__ y,
    float* __restrict__ out, int n_nodes,
    int slab_cap, int ovf_cap)
{
    __shared__ unsigned sorted[SORTMX];    // 11776 B
    __shared__ int hist[CHSZ];
    __shared__ int start[CHSZ + 1];
    __shared__ int cur[CHSZ];

    const int tid = threadIdx.x;
    const int c = blockIdx.x;              // chunk
    const int nbase = c * CHSZ;
    int nspan = CHSZ;
    if (nspan > n_nodes - nbase) nspan = n_nodes - nbase;
    if (nspan <= 0) return;                // uniform: before any sync

    if (tid < CHSZ) hist[tid] = 0;
    __syncthreads();

    int total = cursor[c * CSTR]; if (total > slab_cap) total = slab_cap;
    const uint2* sl = slab + (size_t)c * slab_cap;

    // phase 1: histogram
    for (int i = tid; i < total; i += 1024)
        atomicAdd(&hist[(int)sl[i].y - nbase], 1);
    __syncthreads();

    // phase 2: prefix scan (wave 0; 2 bins per lane)
    if (tid < 64) {
        int a = hist[2 * tid], b = hist[2 * tid + 1];
        int v = a + b;
#pragma unroll
        for (int off = 1; off < 64; off <<= 1) {
            int t = __shfl_up(v, off);
            if (tid >= off) v += t;
        }
        int excl = v - (a + b);
        start[2 * tid]     = excl;
        start[2 * tid + 1] = excl + a;
        cur[2 * tid]       = excl;
        cur[2 * tid + 1]   = excl + a;
        if (tid == 63) start[CHSZ] = v;    // == total
    }
    __syncthreads();

    // phase 3: scatter into sorted order (4B entries; pos < total <= SORTMX)
    for (int i = tid; i < total; i += 1024) {
        uint2 rec = sl[i];
        int pos = atomicAdd(&cur[(int)rec.y - nbase], 1);
        sorted[pos] = rec.x;
    }
    __syncthreads();

    // phase 4: per-node register gather
    const int lane = tid & 63;
    const int wv   = tid >> 6;             // 0..15
    const int s    = lane >> 3;            // record slot 0..7
    const int f    = lane & 7;             // feature group 0..7
    int novf = cursor[OVFC * CSTR]; if (novf > ovf_cap) novf = ovf_cap;

    for (int rel = wv; rel < nspan; rel += 16) {
        int s0 = start[rel], s1 = start[rel + 1];
        float a[8];
#pragma unroll
        for (int j = 0; j < 8; ++j) a[j] = 0.f;

        for (int k = s0 + s; k < s1; k += 8) {
            unsigned e = sorted[k];                        // plain ds_read
            float w = __uint_as_float(e & 0xFFFF0000u);
            ushort8 yv = *(const ushort8*)(y + (size_t)(e & 0xFFFFu) * DOUT + f * 8);
#pragma unroll
            for (int j = 0; j < 8; ++j) a[j] += w * bf2f(yv[j]);
        }

        if (novf > 0) {   // pathological overflow: slot-strided slow path
            for (int i = s; i < novf; i += 8) {
                uint2 rec = ovf[i];
                if ((int)rec.y == nbase + rel) {
                    float w = __uint_as_float(rec.x & 0xFFFF0000u);
                    const unsigned short* yr =
                        y + (size_t)(rec.x & 0xFFFFu) * DOUT + f * 8;
#pragma unroll
                    for (int j = 0; j < 8; ++j) a[j] += w * bf2f(yr[j]);
                }
            }
        }

        // reduce across the 8 slots (lane bits 3..5)
#pragma unroll
        for (int m = 8; m <= 32; m <<= 1)
#pragma unroll
            for (int j = 0; j < 8; ++j) a[j] += __shfl_xor(a[j], m);

        if (s == 0) {     // lanes 0..7 write the 256B fp32 row
            float* orow = out + (size_t)(nbase + rel) * DOUT + f * 8;
            *(float4*)orow       = make_float4(a[0], a[1], a[2], a[3]);
            *(float4*)(orow + 4) = make_float4(a[4], a[5], a[6], a[7]);
        }
    }
}

extern "C" void kernel_launch(void* const* d_in, const int* in_sizes, int n_in,
                              void* d_out, int out_size, void* d_ws, size_t ws_size,
                              hipStream_t stream) {
    const float* x       = (const float*)d_in[0];
    const int*   esrc    = (const int*)d_in[1];
    const int*   edst    = (const int*)d_in[2];
    const float* ew      = (const float*)d_in[3];
    const float* w_bases = (const float*)d_in[4];
    const float* w_rel   = (const float*)d_in[5];
    float* out = (float*)d_out;

    const int n_nodes = in_sizes[0] / KDIM;   // 50000 (< 65536: src fits 16 bits)
    const int n_edges = in_sizes[1];
    const int nc = (n_nodes + CHSZ - 1) / CHSZ;      // 391
    const int cwords = (OVFC + 8) * CSTR;            // 13056 ints (line-padded)

    // Workspace (4-byte words):
    // y bf16: n*32 | wT: 16384 | cursor: cwords | slab: nc*slab_cap*2 | ovf
    size_t wsw = ws_size / 4;
    size_t base = (size_t)n_nodes * 32 + 16384 + cwords;
    size_t avail = (wsw > base) ? wsw - base : 0;
    size_t slab_budget = avail * 7 / 8;
    int slab_cap = (int)(slab_budget / (2 * (size_t)nc));
    // mean edges/chunk = E*CHSZ/N ~ 2048, sigma ~45 -> 2944 = +20 sigma
    if (slab_cap > SORTMX) slab_cap = SORTMX;
    size_t ovf_words = avail - (size_t)2 * nc * slab_cap;
    size_t oc = ovf_words / 2;
    int ovf_cap = (int)(oc > (size_t)n_edges ? (size_t)n_edges : oc);

    unsigned short* y   = (unsigned short*)d_ws;
    unsigned short* wT  = y + (size_t)n_nodes * DOUT;
    int*   cursor       = (int*)(wT + KDIM * DOUT);
    uint2* slab         = (uint2*)(cursor + cwords);  // even word offset: 8B ok
    uint2* ovf          = slab + (size_t)nc * slab_cap;

    weight_kernel<<<(KDIM * DOUT) / 256, 256, 0, stream>>>(
        w_rel, w_bases, wT, cursor);

    const int t_blocks = (n_nodes + 63) / 64;          // 4 waves x 16 nodes
    const int p_blocks = (n_edges + EPB - 1) / EPB;    // binning blocks
    fused_kernel<<<p_blocks + t_blocks, 256, 0, stream>>>(
        x, wT, y, n_nodes,
        esrc, edst, ew, cursor, slab, ovf,
        n_edges, nc, slab_cap, ovf_cap, p_blocks);

    aggregate_kernel<<<nc, 1024, 0, stream>>>(
        slab, ovf, cursor, y, out, n_nodes, slab_cap, ovf_cap);
}

// Round 7
// 213.005 us; speedup vs baseline: 1.0548x; 1.0548x over previous
//
#include <hip/hip_runtime.h>
#include <hip/hip_bf16.h>

// Problem constants (from reference)
#define DFEAT   64
#define NREL    8
#define KDIM    512     // DFEAT * NREL
#define DOUT    64
#define NBASES  4

#define CHSZ    128     // dst-chunk size (power of 2: bin index = d >> 7)
#define NCB_MAX 400     // max chunks with LDS bins / compile-time arrays
#define OVFC    400     // cursor slot index of the overflow counter
#define CSTR    32      // cursor stride in ints = 128 B (one cache line/counter)
#define EPB     2048    // edges per binning block (256 thr x 8)
#define CAPB    9       // LDS bin slots/chunk; lambda 5.24 -> P(>9) ~ 4% fallback
#define SORTMX  2944    // max records sorted per chunk (= slab_cap cap)
#define KH      256     // K-half staged in LDS per pass

typedef short short8 __attribute__((ext_vector_type(8)));    // 8 bf16 = 4 VGPRs
typedef float f32x4  __attribute__((ext_vector_type(4)));    // MFMA C/D frag
typedef unsigned short ushort8 __attribute__((ext_vector_type(8)));  // 16B

// fp32 -> bf16 round-to-nearest-even (bit pattern)
__device__ __forceinline__ unsigned short f2bf(float f) {
    unsigned u = __float_as_uint(f);
    u += 0x7fff + ((u >> 16) & 1);
    return (unsigned short)(u >> 16);
}
__device__ __forceinline__ float bf2f(unsigned short b) {
    return __uint_as_float(((unsigned)b) << 16);
}

// ---------------------------------------------------------------------------
// K1: wT[o][k] = bf16( sum_b w_rel[r,b] * w_bases[b,i,o] ),  k = i*8+r.
// Also zeros the (line-padded) chunk cursors + overflow cursor.
// ---------------------------------------------------------------------------
__global__ __launch_bounds__(256) void weight_kernel(
    const float* __restrict__ w_rel,    // [NREL][NBASES]
    const float* __restrict__ w_bases,  // [NBASES][DFEAT][DOUT]
    unsigned short* __restrict__ wT,    // [DOUT][KDIM] bf16 bits
    int* __restrict__ cursor)
{
    int idx = blockIdx.x * 256 + threadIdx.x;   // 0..32767
    int k = idx & 511;     // i*8 + r
    int o = idx >> 9;      // 0..63
    int i = k >> 3;
    int r = k & 7;
    float s = 0.f;
#pragma unroll
    for (int b = 0; b < NBASES; ++b)
        s += w_rel[r * NBASES + b] * w_bases[(b * DFEAT + i) * DOUT + o];
    wT[o * KDIM + k] = f2bf(s);

    if (idx < (OVFC + 8) * CSTR) cursor[idx] = 0;
}

// LDS overlay (~32.8 KB):
//   transform: wlds = one K-half of wT, XOR-swizzled; ylds overlays it
//              after the final barrier (epilogue staging).
//   bin:       256-chunk LDS bins.
union SharedK2 {
    unsigned short w[DOUT * KH];               // 32768 B, swizzled
    unsigned short ylds[4][16][64];            // 8 KB (epilogue overlay)
    struct {
        uint2 bin[NCB_MAX][CAPB];              // 28.8 KB
        int bcnt[NCB_MAX];                     // 1.6 KB
    } b;
};

// ---------------------------------------------------------------------------
// Fused K2: grid-partitioned. BIN blocks dispatched FIRST.
//   blocks [0, p_blocks):  BIN — LDS bins by dst-chunk (c = d>>7), flushed
//     one-thread-per-bin into per-chunk slabs; line-padded cursors.
//   blocks [p_blocks, ..): transform  Y = Xflat @ Wflat via bf16 MFMA.
//     wT staged in LDS per K-half -> B-fragment waits are lgkmcnt ONLY;
//     the vmcnt queue holds nothing but the half's 16 x-loads, so they
//     retire under the MFMA/ds_read stream (r6's failure mode was wT
//     global loads force-draining x prefetch via in-order vmcnt).
//     LDS reads are XOR-swizzled (byte ^= (row&7)<<4): stride-512B rows
//     would otherwise be a same-bank hotspot for ds_read_b128.
// ---------------------------------------------------------------------------
__global__ __launch_bounds__(256) void fused_kernel(
    const float* __restrict__ x,    // [n_nodes][KDIM] fp32
    const unsigned short* __restrict__ wT,   // [DOUT][KDIM] bf16
    unsigned short* __restrict__ y, // [n_nodes][DOUT] bf16
    int n_nodes,
    const int* __restrict__ esrc, const int* __restrict__ edst,
    const float* __restrict__ ew,
    int* __restrict__ cursor,
    uint2* __restrict__ slab, uint2* __restrict__ ovf,
    int n_edges, int nc, int slab_cap, int ovf_cap, int p_blocks)
{
    const int tid = threadIdx.x;
    __shared__ SharedK2 sh;

    if (blockIdx.x < p_blocks) {
        // ---- bin phase ----
        auto& B = sh.b;
        const int lim = nc < NCB_MAX ? nc : NCB_MAX;
        for (int i = tid; i < lim; i += 256) B.bcnt[i] = 0;
        __syncthreads();

        int e0 = blockIdx.x * EPB + tid;
#pragma unroll
        for (int j = 0; j < EPB / 256; ++j) {
            int e = e0 + j * 256;
            if (e < n_edges) {
                int d = edst[e];
                unsigned entry = (unsigned)(esrc[e] & 0xFFFF)
                               | ((unsigned)f2bf(ew[e]) << 16);
                int c = d >> 7;                        // d / CHSZ
                uint2 rec = make_uint2(entry, (unsigned)d);
                int pos = (c < NCB_MAX) ? atomicAdd(&B.bcnt[c], 1) : CAPB;
                if (pos < CAPB) {
                    B.bin[c][pos] = rec;
                } else {  // LDS bin overflow (~4%): direct append
                    int p = atomicAdd(&cursor[c * CSTR], 1);
                    if (p < slab_cap) slab[(size_t)c * slab_cap + p] = rec;
                    else { int q = atomicAdd(&cursor[OVFC * CSTR], 1);
                           if (q < ovf_cap) ovf[q] = rec; }
                }
            }
        }
        __syncthreads();

        // ---- flush: one thread per bin (atomics on distinct lines) ----
        for (int c = tid; c < lim; c += 256) {
            int n = B.bcnt[c]; if (n > CAPB) n = CAPB;
            int bb = atomicAdd(&cursor[c * CSTR], n);
            uint2* sc = slab + (size_t)c * slab_cap;
            for (int i = 0; i < n; ++i) {
                uint2 rec = B.bin[c][i];
                int p = bb + i;
                if (p < slab_cap) sc[p] = rec;
                else { int q = atomicAdd(&cursor[OVFC * CSTR], 1);
                       if (q < ovf_cap) ovf[q] = rec; }
            }
        }
        return;
    }

    // ---- transform phase ----
    const int bidx = blockIdx.x - p_blocks;
    const int wid  = tid >> 6;
    const int lane = tid & 63;
    const int quad = lane >> 4;    // 0..3
    const int fi   = lane & 15;    // 0..15

    const int node0 = (bidx * 4 + wid) * 16;
    int myrow = node0 + fi;
    if (myrow >= n_nodes) myrow = n_nodes - 1;
    const float* xg = x + (size_t)myrow * KDIM + quad * 8;

    f32x4 acc0 = {0.f, 0.f, 0.f, 0.f};
    f32x4 acc1 = {0.f, 0.f, 0.f, 0.f};
    f32x4 acc2 = {0.f, 0.f, 0.f, 0.f};
    f32x4 acc3 = {0.f, 0.f, 0.f, 0.f};

    const unsigned sx = (unsigned)(fi & 7) << 4;   // read-side XOR (rows
                                                   // fi, fi+16, +32, +48
                                                   // share (row&7) = fi&7)
    char* wb = (char*)sh.w;

#pragma unroll 1
    for (int kh = 0; kh < 2; ++kh) {
        if (kh) __syncthreads();   // protect previous half's reads
        // stage this K-half of wT: 64 rows x 256 cols, swizzled writes
        {
            const unsigned short* wsrc = wT + kh * KH;
            for (int ch = tid; ch < DOUT * (KH / 8); ch += 256) {
                int row = ch >> 5;            // KH/8 = 32 chunks per row
                int col = (ch & 31) * 8;
                unsigned byte = ((unsigned)(row * KH + col) << 1)
                              ^ ((unsigned)(row & 7) << 4);
                *(ushort8*)(wb + byte) =
                    *(const ushort8*)(wsrc + row * KDIM + col);
            }
        }
        __syncthreads();

        // all 16 x-loads of the half issued up front; nothing else in vmcnt
        const float* xh = xg + kh * KH;
        float4 xa[8], xb[8];
#pragma unroll
        for (int u = 0; u < 8; ++u) {
            xa[u] = *(const float4*)(xh + u * 32);
            xb[u] = *(const float4*)(xh + u * 32 + 4);
        }
#pragma unroll
        for (int u = 0; u < 8; ++u) {
            short8 a;
            a[0]=f2bf(xa[u].x); a[1]=f2bf(xa[u].y);
            a[2]=f2bf(xa[u].z); a[3]=f2bf(xa[u].w);
            a[4]=f2bf(xb[u].x); a[5]=f2bf(xb[u].y);
            a[6]=f2bf(xb[u].z); a[7]=f2bf(xb[u].w);
            int kb = u * 32 + quad * 8;
            short8 b0 = *(const short8*)(wb + ((((fi      ) * KH + kb) << 1) ^ sx));
            short8 b1 = *(const short8*)(wb + ((((fi + 16) * KH + kb) << 1) ^ sx));
            short8 b2 = *(const short8*)(wb + ((((fi + 32) * KH + kb) << 1) ^ sx));
            short8 b3 = *(const short8*)(wb + ((((fi + 48) * KH + kb) << 1) ^ sx));
            acc0 = __builtin_amdgcn_mfma_f32_16x16x32_bf16(a, b0, acc0, 0, 0, 0);
            acc1 = __builtin_amdgcn_mfma_f32_16x16x32_bf16(a, b1, acc1, 0, 0, 0);
            acc2 = __builtin_amdgcn_mfma_f32_16x16x32_bf16(a, b2, acc2, 0, 0, 0);
            acc3 = __builtin_amdgcn_mfma_f32_16x16x32_bf16(a, b3, acc3, 0, 0, 0);
        }
    }

    __syncthreads();   // all waves done reading sh.w -> safe to overlay ylds

    // epilogue: C layout col=fi, row=quad*4+r -> stage to LDS, store b128
#pragma unroll
    for (int r = 0; r < 4; ++r) {
        int n = quad * 4 + r;
        sh.ylds[wid][n][fi]      = f2bf(acc0[r]);
        sh.ylds[wid][n][16 + fi] = f2bf(acc1[r]);
        sh.ylds[wid][n][32 + fi] = f2bf(acc2[r]);
        sh.ylds[wid][n][48 + fi] = f2bf(acc3[r]);
    }
    __syncthreads();   // uniform: no transform wave returned early

    int nl = lane >> 2;            // node_local 0..15
    int cg = (lane & 3) * 16;      // 16-short chunk within the 64-col row
    int node = node0 + nl;
    if (node < n_nodes) {
        ushort8 v0 = *(const ushort8*)&sh.ylds[wid][nl][cg];
        ushort8 v1 = *(const ushort8*)&sh.ylds[wid][nl][cg + 8];
        unsigned short* yr = y + (size_t)node * DOUT + cg;
        *(ushort8*)yr       = v0;
        *(ushort8*)(yr + 8) = v1;
    }
}

// ---------------------------------------------------------------------------
// K3: aggregate — counting-sort in LDS, then pure-register gather.
// (unchanged from r5/r6 — it is no longer in the top-5)
// ---------------------------------------------------------------------------
__global__ __launch_bounds__(1024, 4) void aggregate_kernel(
    const uint2* __restrict__ slab, const uint2* __restrict__ ovf,
    const int* __restrict__ cursor,
    const unsigned short* __restrict__ y,
    float* __restrict__ out, int n_nodes,
    int slab_cap, int ovf_cap)
{
    __shared__ unsigned sorted[SORTMX];    // 11776 B
    __shared__ int hist[CHSZ];
    __shared__ int start[CHSZ + 1];
    __shared__ int cur[CHSZ];

    const int tid = threadIdx.x;
    const int c = blockIdx.x;              // chunk
    const int nbase = c * CHSZ;
    int nspan = CHSZ;
    if (nspan > n_nodes - nbase) nspan = n_nodes - nbase;
    if (nspan <= 0) return;                // uniform: before any sync

    if (tid < CHSZ) hist[tid] = 0;
    __syncthreads();

    int total = cursor[c * CSTR]; if (total > slab_cap) total = slab_cap;
    const uint2* sl = slab + (size_t)c * slab_cap;

    // phase 1: histogram
    for (int i = tid; i < total; i += 1024)
        atomicAdd(&hist[(int)sl[i].y - nbase], 1);
    __syncthreads();

    // phase 2: prefix scan (wave 0; 2 bins per lane)
    if (tid < 64) {
        int a = hist[2 * tid], b = hist[2 * tid + 1];
        int v = a + b;
#pragma unroll
        for (int off = 1; off < 64; off <<= 1) {
            int t = __shfl_up(v, off);
            if (tid >= off) v += t;
        }
        int excl = v - (a + b);
        start[2 * tid]     = excl;
        start[2 * tid + 1] = excl + a;
        cur[2 * tid]       = excl;
        cur[2 * tid + 1]   = excl + a;
        if (tid == 63) start[CHSZ] = v;    // == total
    }
    __syncthreads();

    // phase 3: scatter into sorted order (4B entries; pos < total <= SORTMX)
    for (int i = tid; i < total; i += 1024) {
        uint2 rec = sl[i];
        int pos = atomicAdd(&cur[(int)rec.y - nbase], 1);
        sorted[pos] = rec.x;
    }
    __syncthreads();

    // phase 4: per-node register gather
    const int lane = tid & 63;
    const int wv   = tid >> 6;             // 0..15
    const int s    = lane >> 3;            // record slot 0..7
    const int f    = lane & 7;             // feature group 0..7
    int novf = cursor[OVFC * CSTR]; if (novf > ovf_cap) novf = ovf_cap;

    for (int rel = wv; rel < nspan; rel += 16) {
        int s0 = start[rel], s1 = start[rel + 1];
        float a[8];
#pragma unroll
        for (int j = 0; j < 8; ++j) a[j] = 0.f;

        for (int k = s0 + s; k < s1; k += 8) {
            unsigned e = sorted[k];                        // plain ds_read
            float w = __uint_as_float(e & 0xFFFF0000u);
            ushort8 yv = *(const ushort8*)(y + (size_t)(e & 0xFFFFu) * DOUT + f * 8);
#pragma unroll
            for (int j = 0; j < 8; ++j) a[j] += w * bf2f(yv[j]);
        }

        if (novf > 0) {   // pathological overflow: slot-strided slow path
            for (int i = s; i < novf; i += 8) {
                uint2 rec = ovf[i];
                if ((int)rec.y == nbase + rel) {
                    float w = __uint_as_float(rec.x & 0xFFFF0000u);
                    const unsigned short* yr =
                        y + (size_t)(rec.x & 0xFFFFu) * DOUT + f * 8;
#pragma unroll
                    for (int j = 0; j < 8; ++j) a[j] += w * bf2f(yr[j]);
                }
            }
        }

        // reduce across the 8 slots (lane bits 3..5)
#pragma unroll
        for (int m = 8; m <= 32; m <<= 1)
#pragma unroll
            for (int j = 0; j < 8; ++j) a[j] += __shfl_xor(a[j], m);

        if (s == 0) {     // lanes 0..7 write the 256B fp32 row
            float* orow = out + (size_t)(nbase + rel) * DOUT + f * 8;
            *(float4*)orow       = make_float4(a[0], a[1], a[2], a[3]);
            *(float4*)(orow + 4) = make_float4(a[4], a[5], a[6], a[7]);
        }
    }
}

extern "C" void kernel_launch(void* const* d_in, const int* in_sizes, int n_in,
                              void* d_out, int out_size, void* d_ws, size_t ws_size,
                              hipStream_t stream) {
    const float* x       = (const float*)d_in[0];
    const int*   esrc    = (const int*)d_in[1];
    const int*   edst    = (const int*)d_in[2];
    const float* ew      = (const float*)d_in[3];
    const float* w_bases = (const float*)d_in[4];
    const float* w_rel   = (const float*)d_in[5];
    float* out = (float*)d_out;

    const int n_nodes = in_sizes[0] / KDIM;   // 50000 (< 65536: src fits 16 bits)
    const int n_edges = in_sizes[1];
    const int nc = (n_nodes + CHSZ - 1) / CHSZ;      // 391
    const int cwords = (OVFC + 8) * CSTR;            // 13056 ints (line-padded)

    // Workspace (4-byte words):
    // y bf16: n*32 | wT: 16384 | cursor: cwords | slab: nc*slab_cap*2 | ovf
    size_t wsw = ws_size / 4;
    size_t base = (size_t)n_nodes * 32 + 16384 + cwords;
    size_t avail = (wsw > base) ? wsw - base : 0;
    size_t slab_budget = avail * 7 / 8;
    int slab_cap = (int)(slab_budget / (2 * (size_t)nc));
    // mean edges/chunk = E*CHSZ/N ~ 2048, sigma ~45 -> 2944 = +20 sigma
    if (slab_cap > SORTMX) slab_cap = SORTMX;
    size_t ovf_words = avail - (size_t)2 * nc * slab_cap;
    size_t oc = ovf_words / 2;
    int ovf_cap = (int)(oc > (size_t)n_edges ? (size_t)n_edges : oc);

    unsigned short* y   = (unsigned short*)d_ws;
    unsigned short* wT  = y + (size_t)n_nodes * DOUT;
    int*   cursor       = (int*)(wT + KDIM * DOUT);
    uint2* slab         = (uint2*)(cursor + cwords);  // even word offset: 8B ok
    uint2* ovf          = slab + (size_t)nc * slab_cap;

    weight_kernel<<<(KDIM * DOUT) / 256, 256, 0, stream>>>(
        w_rel, w_bases, wT, cursor);

    const int t_blocks = (n_nodes + 63) / 64;          // 4 waves x 16 nodes
    const int p_blocks = (n_edges + EPB - 1) / EPB;    // binning blocks
    fused_kernel<<<p_blocks + t_blocks, 256, 0, stream>>>(
        x, wT, y, n_nodes,
        esrc, edst, ew, cursor, slab, ovf,
        n_edges, nc, slab_cap, ovf_cap, p_blocks);

    aggregate_kernel<<<nc, 1024, 0, stream>>>(
        slab, ovf, cursor, y, out, n_nodes, slab_cap, ovf_cap);
}

// Round 9
// 204.320 us; speedup vs baseline: 1.0996x; 1.0425x over previous
//
#include <hip/hip_runtime.h>
#include <hip/hip_bf16.h>

// Problem constants (from reference)
#define DFEAT   64
#define NREL    8
#define KDIM    512     // DFEAT * NREL
#define DOUT    64
#define NBASES  4

#define CHSZ    128     // dst-chunk size (power of 2: bin index = d >> 7)
#define NCB_MAX 400     // max chunks with LDS bins / compile-time arrays
#define OVFC    400     // cursor slot index of the overflow counter
#define CSTR    32      // cursor stride in ints = 128 B (one cache line/counter)
#define EPB     2048    // edges per binning block (256 thr x 8)
#define CAPB    9       // LDS bin slots/chunk; lambda 5.24 -> P(>9) ~ 4% fallback
#define SORTMX  2944    // max records sorted per chunk (= slab_cap cap)
#define KH      256     // K-half staged in LDS per pass

typedef short short8 __attribute__((ext_vector_type(8)));    // 8 bf16 = 4 VGPRs
typedef float f32x4  __attribute__((ext_vector_type(4)));    // MFMA C/D frag
typedef unsigned short ushort8 __attribute__((ext_vector_type(8)));  // 16B

// fp32 -> bf16 round-to-nearest-even (bit pattern)
__device__ __forceinline__ unsigned short f2bf(float f) {
    unsigned u = __float_as_uint(f);
    u += 0x7fff + ((u >> 16) & 1);
    return (unsigned short)(u >> 16);
}
__device__ __forceinline__ float bf2f(unsigned short b) {
    return __uint_as_float(((unsigned)b) << 16);
}

// ---------------------------------------------------------------------------
// K1: wT[o][k] = bf16( sum_b w_rel[r,b] * w_bases[b,i,o] ),  k = i*8+r.
// Also zeros the (line-padded) chunk cursors + overflow cursor.
// ---------------------------------------------------------------------------
__global__ __launch_bounds__(256) void weight_kernel(
    const float* __restrict__ w_rel,    // [NREL][NBASES]
    const float* __restrict__ w_bases,  // [NBASES][DFEAT][DOUT]
    unsigned short* __restrict__ wT,    // [DOUT][KDIM] bf16 bits
    int* __restrict__ cursor)
{
    int idx = blockIdx.x * 256 + threadIdx.x;   // 0..32767
    int k = idx & 511;     // i*8 + r
    int o = idx >> 9;      // 0..63
    int i = k >> 3;
    int r = k & 7;
    float s = 0.f;
#pragma unroll
    for (int b = 0; b < NBASES; ++b)
        s += w_rel[r * NBASES + b] * w_bases[(b * DFEAT + i) * DOUT + o];
    wT[o * KDIM + k] = f2bf(s);

    if (idx < (OVFC + 8) * CSTR) cursor[idx] = 0;
}

// LDS overlay (~32.8 KB):
//   transform: w = one K-half of wT, ROTATION-swizzled; ylds overlays it
//              after the final barrier (epilogue staging).
//   bin:       LDS bins by dst-chunk.
union SharedK2 {
    unsigned short w[DOUT * KH];               // 32768 B, swizzled
    unsigned short ylds[4][16][64];            // 8 KB (epilogue overlay)
    struct {
        uint2 bin[NCB_MAX][CAPB];              // 28.8 KB
        int bcnt[NCB_MAX];                     // 1.6 KB
    } b;
};

// ---------------------------------------------------------------------------
// Fused K2: grid-partitioned. BIN blocks dispatched FIRST.
//   blocks [0, p_blocks):  BIN — LDS bins by dst-chunk (c = d>>7), flushed
//     one-thread-per-bin into per-chunk slabs; line-padded cursors.
//   blocks [p_blocks, ..): transform  Y = Xflat @ Wflat via bf16 MFMA.
//     - wT staged per K-half -> B-waits are lgkmcnt-only (r7 win, kept).
//     - ROTATION swizzle sigma(cb,row) = (cb + 2*row) & 31:
//       read slot = (4u + quad + 2*fi) & 31 -> exactly 2 lanes / 16B slot
//       (r7's XOR (row&7)<<4 collapsed to 8 slots = 8-way conflict).
//     - x-loads issued FIRST, pinned live via keep-alive asm on the four
//       32-bit components (r8: float4 operands don't compile; scalar
//       components do, and keep the whole vector live). x latency hides
//       under W-stage + barrier.
// ---------------------------------------------------------------------------
__global__ __launch_bounds__(256) void fused_kernel(
    const float* __restrict__ x,    // [n_nodes][KDIM] fp32
    const unsigned short* __restrict__ wT,   // [DOUT][KDIM] bf16
    unsigned short* __restrict__ y, // [n_nodes][DOUT] bf16
    int n_nodes,
    const int* __restrict__ esrc, const int* __restrict__ edst,
    const float* __restrict__ ew,
    int* __restrict__ cursor,
    uint2* __restrict__ slab, uint2* __restrict__ ovf,
    int n_edges, int nc, int slab_cap, int ovf_cap, int p_blocks)
{
    const int tid = threadIdx.x;
    __shared__ SharedK2 sh;

    if (blockIdx.x < p_blocks) {
        // ---- bin phase ----
        auto& B = sh.b;
        const int lim = nc < NCB_MAX ? nc : NCB_MAX;
        for (int i = tid; i < lim; i += 256) B.bcnt[i] = 0;
        __syncthreads();

        int e0 = blockIdx.x * EPB + tid;
#pragma unroll
        for (int j = 0; j < EPB / 256; ++j) {
            int e = e0 + j * 256;
            if (e < n_edges) {
                int d = edst[e];
                unsigned entry = (unsigned)(esrc[e] & 0xFFFF)
                               | ((unsigned)f2bf(ew[e]) << 16);
                int c = d >> 7;                        // d / CHSZ
                uint2 rec = make_uint2(entry, (unsigned)d);
                int pos = (c < NCB_MAX) ? atomicAdd(&B.bcnt[c], 1) : CAPB;
                if (pos < CAPB) {
                    B.bin[c][pos] = rec;
                } else {  // LDS bin overflow (~4%): direct append
                    int p = atomicAdd(&cursor[c * CSTR], 1);
                    if (p < slab_cap) slab[(size_t)c * slab_cap + p] = rec;
                    else { int q = atomicAdd(&cursor[OVFC * CSTR], 1);
                           if (q < ovf_cap) ovf[q] = rec; }
                }
            }
        }
        __syncthreads();

        // ---- flush: one thread per bin (atomics on distinct lines) ----
        for (int c = tid; c < lim; c += 256) {
            int n = B.bcnt[c]; if (n > CAPB) n = CAPB;
            int bb = atomicAdd(&cursor[c * CSTR], n);
            uint2* sc = slab + (size_t)c * slab_cap;
            for (int i = 0; i < n; ++i) {
                uint2 rec = B.bin[c][i];
                int p = bb + i;
                if (p < slab_cap) sc[p] = rec;
                else { int q = atomicAdd(&cursor[OVFC * CSTR], 1);
                       if (q < ovf_cap) ovf[q] = rec; }
            }
        }
        return;
    }

    // ---- transform phase ----
    const int bidx = blockIdx.x - p_blocks;
    const int wid  = tid >> 6;
    const int lane = tid & 63;
    const int quad = lane >> 4;    // 0..3
    const int fi   = lane & 15;    // 0..15

    const int node0 = (bidx * 4 + wid) * 16;
    int myrow = node0 + fi;
    if (myrow >= n_nodes) myrow = n_nodes - 1;
    const float* xg = x + (size_t)myrow * KDIM + quad * 8;

    f32x4 acc0 = {0.f, 0.f, 0.f, 0.f};
    f32x4 acc1 = {0.f, 0.f, 0.f, 0.f};
    f32x4 acc2 = {0.f, 0.f, 0.f, 0.f};
    f32x4 acc3 = {0.f, 0.f, 0.f, 0.f};

    const int t2 = quad + 2 * fi;     // read-side rotation term (mod 32)
    char* wb = (char*)sh.w;

#pragma unroll 1
    for (int kh = 0; kh < 2; ++kh) {
        if (kh) __syncthreads();   // protect previous half's reads

        // 1) issue ALL 16 x-loads of this half, pin them live (MLP)
        const float* xh = xg + kh * KH;
        float4 xa[8], xb[8];
#pragma unroll
        for (int u = 0; u < 8; ++u) {
            xa[u] = *(const float4*)(xh + u * 32);
            xb[u] = *(const float4*)(xh + u * 32 + 4);
        }
#pragma unroll
        for (int u = 0; u < 8; ++u) {
            asm volatile("" :: "v"(xa[u].x), "v"(xa[u].y),
                               "v"(xa[u].z), "v"(xa[u].w),
                               "v"(xb[u].x), "v"(xb[u].y),
                               "v"(xb[u].z), "v"(xb[u].w));
        }

        // 2) stage this K-half of wT (rotation-swizzled)
        {
            const unsigned short* wsrc = wT + kh * KH;
#pragma unroll
            for (int it = 0; it < (DOUT * (KH / 8)) / 256; ++it) {
                int ch = it * 256 + tid;
                int row = ch >> 5;            // 0..63
                int cb  = ch & 31;            // 8-short chunk index
                unsigned byte = ((unsigned)row << 9)
                              + ((unsigned)((cb + 2 * row) & 31) << 4);
                *(ushort8*)(wb + byte) =
                    *(const ushort8*)(wsrc + row * KDIM + cb * 8);
            }
        }
        __syncthreads();

        // 3) compute: B via conflict-free ds_read_b128, A from registers
#pragma unroll
        for (int u = 0; u < 8; ++u) {
            short8 a;
            a[0]=f2bf(xa[u].x); a[1]=f2bf(xa[u].y);
            a[2]=f2bf(xa[u].z); a[3]=f2bf(xa[u].w);
            a[4]=f2bf(xb[u].x); a[5]=f2bf(xb[u].y);
            a[6]=f2bf(xb[u].z); a[7]=f2bf(xb[u].w);
            // sigma identical for all 4 matrices: 2*(fi+16m) == 2*fi mod 32
            unsigned co = (unsigned)((u * 4 + t2) & 31) << 4;
            short8 b0 = *(const short8*)(wb + (((unsigned)(fi     ) << 9) + co));
            short8 b1 = *(const short8*)(wb + (((unsigned)(fi + 16) << 9) + co));
            short8 b2 = *(const short8*)(wb + (((unsigned)(fi + 32) << 9) + co));
            short8 b3 = *(const short8*)(wb + (((unsigned)(fi + 48) << 9) + co));
            acc0 = __builtin_amdgcn_mfma_f32_16x16x32_bf16(a, b0, acc0, 0, 0, 0);
            acc1 = __builtin_amdgcn_mfma_f32_16x16x32_bf16(a, b1, acc1, 0, 0, 0);
            acc2 = __builtin_amdgcn_mfma_f32_16x16x32_bf16(a, b2, acc2, 0, 0, 0);
            acc3 = __builtin_amdgcn_mfma_f32_16x16x32_bf16(a, b3, acc3, 0, 0, 0);
        }
    }

    __syncthreads();   // all waves done reading sh.w -> safe to overlay ylds

    // epilogue: C layout col=fi, row=quad*4+r -> stage to LDS, store b128
#pragma unroll
    for (int r = 0; r < 4; ++r) {
        int n = quad * 4 + r;
        sh.ylds[wid][n][fi]      = f2bf(acc0[r]);
        sh.ylds[wid][n][16 + fi] = f2bf(acc1[r]);
        sh.ylds[wid][n][32 + fi] = f2bf(acc2[r]);
        sh.ylds[wid][n][48 + fi] = f2bf(acc3[r]);
    }
    __syncthreads();   // uniform: no transform wave returned early

    int nl = lane >> 2;            // node_local 0..15
    int cg = (lane & 3) * 16;      // 16-short chunk within the 64-col row
    int node = node0 + nl;
    if (node < n_nodes) {
        ushort8 v0 = *(const ushort8*)&sh.ylds[wid][nl][cg];
        ushort8 v1 = *(const ushort8*)&sh.ylds[wid][nl][cg + 8];
        unsigned short* yr = y + (size_t)node * DOUT + cg;
        *(ushort8*)yr       = v0;
        *(ushort8*)(yr + 8) = v1;
    }
}

// ---------------------------------------------------------------------------
// K3: aggregate — counting-sort in LDS, then pure-register gather.
// (unchanged from r5-r7 — no longer in the top-5)
// ---------------------------------------------------------------------------
__global__ __launch_bounds__(1024, 4) void aggregate_kernel(
    const uint2* __restrict__ slab, const uint2* __restrict__ ovf,
    const int* __restrict__ cursor,
    const unsigned short* __restrict__ y,
    float* __restrict__ out, int n_nodes,
    int slab_cap, int ovf_cap)
{
    __shared__ unsigned sorted[SORTMX];    // 11776 B
    __shared__ int hist[CHSZ];
    __shared__ int start[CHSZ + 1];
    __shared__ int cur[CHSZ];

    const int tid = threadIdx.x;
    const int c = blockIdx.x;              // chunk
    const int nbase = c * CHSZ;
    int nspan = CHSZ;
    if (nspan > n_nodes - nbase) nspan = n_nodes - nbase;
    if (nspan <= 0) return;                // uniform: before any sync

    if (tid < CHSZ) hist[tid] = 0;
    __syncthreads();

    int total = cursor[c * CSTR]; if (total > slab_cap) total = slab_cap;
    const uint2* sl = slab + (size_t)c * slab_cap;

    // phase 1: histogram
    for (int i = tid; i < total; i += 1024)
        atomicAdd(&hist[(int)sl[i].y - nbase], 1);
    __syncthreads();

    // phase 2: prefix scan (wave 0; 2 bins per lane)
    if (tid < 64) {
        int a = hist[2 * tid], b = hist[2 * tid + 1];
        int v = a + b;
#pragma unroll
        for (int off = 1; off < 64; off <<= 1) {
            int t = __shfl_up(v, off);
            if (tid >= off) v += t;
        }
        int excl = v - (a + b);
        start[2 * tid]     = excl;
        start[2 * tid + 1] = excl + a;
        cur[2 * tid]       = excl;
        cur[2 * tid + 1]   = excl + a;
        if (tid == 63) start[CHSZ] = v;    // == total
    }
    __syncthreads();

    // phase 3: scatter into sorted order (4B entries; pos < total <= SORTMX)
    for (int i = tid; i < total; i += 1024) {
        uint2 rec = sl[i];
        int pos = atomicAdd(&cur[(int)rec.y - nbase], 1);
        sorted[pos] = rec.x;
    }
    __syncthreads();

    // phase 4: per-node register gather
    const int lane = tid & 63;
    const int wv   = tid >> 6;             // 0..15
    const int s    = lane >> 3;            // record slot 0..7
    const int f    = lane & 7;             // feature group 0..7
    int novf = cursor[OVFC * CSTR]; if (novf > ovf_cap) novf = ovf_cap;

    for (int rel = wv; rel < nspan; rel += 16) {
        int s0 = start[rel], s1 = start[rel + 1];
        float a[8];
#pragma unroll
        for (int j = 0; j < 8; ++j) a[j] = 0.f;

        for (int k = s0 + s; k < s1; k += 8) {
            unsigned e = sorted[k];                        // plain ds_read
            float w = __uint_as_float(e & 0xFFFF0000u);
            ushort8 yv = *(const ushort8*)(y + (size_t)(e & 0xFFFFu) * DOUT + f * 8);
#pragma unroll
            for (int j = 0; j < 8; ++j) a[j] += w * bf2f(yv[j]);
        }

        if (novf > 0) {   // pathological overflow: slot-strided slow path
            for (int i = s; i < novf; i += 8) {
                uint2 rec = ovf[i];
                if ((int)rec.y == nbase + rel) {
                    float w = __uint_as_float(rec.x & 0xFFFF0000u);
                    const unsigned short* yr =
                        y + (size_t)(rec.x & 0xFFFFu) * DOUT + f * 8;
#pragma unroll
                    for (int j = 0; j < 8; ++j) a[j] += w * bf2f(yr[j]);
                }
            }
        }

        // reduce across the 8 slots (lane bits 3..5)
#pragma unroll
        for (int m = 8; m <= 32; m <<= 1)
#pragma unroll
            for (int j = 0; j < 8; ++j) a[j] += __shfl_xor(a[j], m);

        if (s == 0) {     // lanes 0..7 write the 256B fp32 row
            float* orow = out + (size_t)(nbase + rel) * DOUT + f * 8;
            *(float4*)orow       = make_float4(a[0], a[1], a[2], a[3]);
            *(float4*)(orow + 4) = make_float4(a[4], a[5], a[6], a[7]);
        }
    }
}

extern "C" void kernel_launch(void* const* d_in, const int* in_sizes, int n_in,
                              void* d_out, int out_size, void* d_ws, size_t ws_size,
                              hipStream_t stream) {
    const float* x       = (const float*)d_in[0];
    const int*   esrc    = (const int*)d_in[1];
    const int*   edst    = (const int*)d_in[2];
    const float* ew      = (const float*)d_in[3];
    const float* w_bases = (const float*)d_in[4];
    const float* w_rel   = (const float*)d_in[5];
    float* out = (float*)d_out;

    const int n_nodes = in_sizes[0] / KDIM;   // 50000 (< 65536: src fits 16 bits)
    const int n_edges = in_sizes[1];
    const int nc = (n_nodes + CHSZ - 1) / CHSZ;      // 391
    const int cwords = (OVFC + 8) * CSTR;            // 13056 ints (line-padded)

    // Workspace (4-byte words):
    // y bf16: n*32 | wT: 16384 | cursor: cwords | slab: nc*slab_cap*2 | ovf
    size_t wsw = ws_size / 4;
    size_t base = (size_t)n_nodes * 32 + 16384 + cwords;
    size_t avail = (wsw > base) ? wsw - base : 0;
    size_t slab_budget = avail * 7 / 8;
    int slab_cap = (int)(slab_budget / (2 * (size_t)nc));
    // mean edges/chunk = E*CHSZ/N ~ 2048, sigma ~45 -> 2944 = +20 sigma
    if (slab_cap > SORTMX) slab_cap = SORTMX;
    size_t ovf_words = avail - (size_t)2 * nc * slab_cap;
    size_t oc = ovf_words / 2;
    int ovf_cap = (int)(oc > (size_t)n_edges ? (size_t)n_edges : oc);

    unsigned short* y   = (unsigned short*)d_ws;
    unsigned short* wT  = y + (size_t)n_nodes * DOUT;
    int*   cursor       = (int*)(wT + KDIM * DOUT);
    uint2* slab         = (uint2*)(cursor + cwords);  // even word offset: 8B ok
    uint2* ovf          = slab + (size_t)nc * slab_cap;

    weight_kernel<<<(KDIM * DOUT) / 256, 256, 0, stream>>>(
        w_rel, w_bases, wT, cursor);

    const int t_blocks = (n_nodes + 63) / 64;          // 4 waves x 16 nodes
    const int p_blocks = (n_edges + EPB - 1) / EPB;    // binning blocks
    fused_kernel<<<p_blocks + t_blocks, 256, 0, stream>>>(
        x, wT, y, n_nodes,
        esrc, edst, ew, cursor, slab, ovf,
        n_edges, nc, slab_cap, ovf_cap, p_blocks);

    aggregate_kernel<<<nc, 1024, 0, stream>>>(
        slab, ovf, cursor, y, out, n_nodes, slab_cap, ovf_cap);
}